// Round 8
// baseline (405.683 us; speedup 1.0000x reference)
//
#include <hip/hip_runtime.h>
#include <hip/hip_bf16.h>
#include <hip/hip_fp16.h>

// Problem constants (match reference)
#define N_NODES 100000
#define N_EDGES 1600000
#define N_GRAPHS 128

// Counting-sort CSR build parameters (pad-8)
#define BSH 9                 // bucket = col >> 9
#define BNODES 512            // nodes per bucket
#define NB 196                // ceil(100000 / 512)
#define CAP 12288             // static per-bucket csr/record capacity (elems)
#define BLK 512               // histogram blocks
#define EPB (N_EDGES / BLK)   // 3125 edges per block (exact)
#define RECMAX 10240          // max records per bucket held in LDS

#define SPLIT 4               // pooling blocks per graph

typedef __attribute__((ext_vector_type(8))) _Float16 v8h;
typedef __attribute__((ext_vector_type(4))) float v4f;
typedef __attribute__((ext_vector_type(4))) int vi4;
typedef __attribute__((ext_vector_type(2))) int vi2;
typedef __attribute__((ext_vector_type(4))) float vf4;

// unpack 2 halves packed in an int -> float2 (value-level)
__device__ __forceinline__ float2 h2f(int bits) {
    return __half22float2(__builtin_bit_cast(__half2, bits));
}

__device__ __forceinline__ v8h zero8h() {
    v8h z = {(_Float16)0, (_Float16)0, (_Float16)0, (_Float16)0,
             (_Float16)0, (_Float16)0, (_Float16)0, (_Float16)0};
    return z;
}

// ---------------- CSR build (no global atomics) ----------------

__global__ __launch_bounds__(256) void k_hist(const int* __restrict__ col,
                                              int* __restrict__ hist_t,
                                              __half* __restrict__ h16a,
                                              __half* __restrict__ h16b,
                                              int* __restrict__ done) {
    __shared__ int h[NB];
    const int t = threadIdx.x, b = blockIdx.x;
    if (b == 0) {                              // zero sentinels + pool counter
        if (t < 64) {
            h16a[(size_t)N_NODES * 64 + t] = __float2half(0.0f);
            h16b[(size_t)N_NODES * 64 + t] = __float2half(0.0f);
        }
        if (t == 64) *done = 0;
    }
    for (int i = t; i < NB; i += 256) h[i] = 0;
    __syncthreads();
    const int e0 = b * EPB;
    for (int i = t; i < EPB; i += 256) atomicAdd(&h[col[e0 + i] >> BSH], 1);
    __syncthreads();
    for (int i = t; i < NB; i += 256) hist_t[i * BLK + b] = h[i];
}

__global__ __launch_bounds__(512) void k_cursors(const int* __restrict__ hist_t,
                                                 int* __restrict__ cursors,
                                                 int* __restrict__ bcnt) {
    __shared__ int s[BLK];
    const int t = threadIdx.x, bin = blockIdx.x;
    const int v = hist_t[bin * BLK + t];
    s[t] = v; __syncthreads();
    for (int off = 1; off < BLK; off <<= 1) {
        int a = (t >= off) ? s[t - off] : 0;
        __syncthreads(); s[t] += a; __syncthreads();
    }
    cursors[bin * BLK + t] = bin * CAP + s[t] - v;   // exclusive + static base
    if (t == BLK - 1) bcnt[bin] = s[t];
}

__global__ __launch_bounds__(256) void k_mid(const int* __restrict__ row,
                                             const int* __restrict__ col,
                                             const int* __restrict__ cursors,
                                             int* __restrict__ bedges) {
    __shared__ int cur[NB];
    const int t = threadIdx.x, b = blockIdx.x;
    for (int i = t; i < NB; i += 256) cur[i] = cursors[i * BLK + b];
    __syncthreads();
    const int e0 = b * EPB;
    for (int i = t; i < EPB; i += 256) {
        const int c = col[e0 + i];
        const int r = row[e0 + i];
        const int pos = atomicAdd(&cur[c >> BSH], 1);
        bedges[pos] = r | ((c & (BNODES - 1)) << 17);   // row<2^17, lcol 9 bits
    }
}

__global__ __launch_bounds__(512) void k_build(const int* __restrict__ bedges,
                                               const int* __restrict__ bcnt,
                                               int* __restrict__ csr,
                                               int* __restrict__ offs,
                                               int* __restrict__ deg_c,
                                               float* __restrict__ dinv) {
    __shared__ int rec[RECMAX];
    __shared__ int deg[BNODES];
    __shared__ int offx[BNODES];
    __shared__ int cur[BNODES];
    const int t = threadIdx.x, bin = blockIdx.x;
    const int base = bin * CAP;
    const int cnt = bcnt[bin];
    const int vb = bin << BSH;
    const int nn = min(BNODES, N_NODES - vb);
    for (int i = t; i < cnt; i += 512) rec[i] = bedges[base + i];
    deg[t] = 0;
    __syncthreads();                 // all record loads done before any csr write
    for (int i = t; i < cnt; i += 512) atomicAdd(&deg[(rec[i] >> 17) & (BNODES - 1)], 1);
    __syncthreads();
    const int d = (t < nn) ? deg[t] : 0;
    const int pd = (d + 7) & ~7;     // pad each segment to x8
    offx[t] = pd; __syncthreads();
    for (int off = 1; off < BNODES; off <<= 1) {
        int a = (t >= off) ? offx[t - off] : 0;
        __syncthreads(); offx[t] += a; __syncthreads();
    }
    const int myoff = offx[t] - pd;  // exclusive
    cur[t] = myoff;
    if (t < nn) {
        offs[vb + t] = base + myoff;
        deg_c[vb + t] = d;
        dinv[vb + t] = (d > 0) ? rsqrtf((float)d) : 0.0f;
        for (int j = d; j < pd; j++) csr[base + myoff + j] = N_NODES;  // sentinel
    }
    __syncthreads();
    for (int i = t; i < cnt; i += 512) {
        const int r = rec[i];
        const int pos = atomicAdd(&cur[(r >> 17) & (BNODES - 1)], 1);
        csr[base + pos] = r & 0x1FFFF;
    }
}

// ---------------- MFMA GEMM (layer 1): H16[n][64] = fp16(dinv[n] * (X[n,:] @ W)) ------
// 64-node x 64-ch tile, 4 waves. Only W in LDS (hi+lo fp16 split); A-fragments
// loaded directly from global. One barrier.

template <int CIN>
__global__ __launch_bounds__(256) void k_gemm(const float* __restrict__ X,
                                              const float* __restrict__ W,
                                              const float* __restrict__ dinv,
                                              __half* __restrict__ H16) {
    constexpr int SBK = CIN + 8;                 // padded k-extent
    __shared__ __align__(16) _Float16 sBh[64 * SBK];
    __shared__ __align__(16) _Float16 sBl[64 * SBK];
    const int t = threadIdx.x;
    const int w = t >> 6, lane = t & 63;
    const int quad = lane >> 4, l16 = lane & 15;
    const int nb = blockIdx.x * 64;

    // stage all W [CIN x 64] -> transposed hi/lo [c][k]
    for (int i = t; i < CIN * 16; i += 256) {
        const int k = i >> 4, c4 = (i & 15) * 4;
        const float4 wv = *reinterpret_cast<const float4*>(W + (size_t)k * 64 + c4);
        const float wf[4] = {wv.x, wv.y, wv.z, wv.w};
        #pragma unroll
        for (int j = 0; j < 4; j++) {
            const _Float16 hi = (_Float16)wf[j];
            sBh[(c4 + j) * SBK + k] = hi;
            sBl[(c4 + j) * SBK + k] = (_Float16)(wf[j] - (float)hi);
        }
    }
    __syncthreads();

    const int gn = nb + w * 16 + l16;            // A-fragment row for this lane
    v4f acc[4] = {};                             // [ntile]

    #pragma unroll
    for (int k0 = 0; k0 < CIN; k0 += 32) {
        const int kb = k0 + quad * 8;
        v8h afr;
        if (gn < N_NODES) {
            const float4 u0 = *reinterpret_cast<const float4*>(X + (size_t)gn * CIN + kb);
            const float4 u1 = *reinterpret_cast<const float4*>(X + (size_t)gn * CIN + kb + 4);
            afr[0] = (_Float16)u0.x; afr[1] = (_Float16)u0.y;
            afr[2] = (_Float16)u0.z; afr[3] = (_Float16)u0.w;
            afr[4] = (_Float16)u1.x; afr[5] = (_Float16)u1.y;
            afr[6] = (_Float16)u1.z; afr[7] = (_Float16)u1.w;
        } else {
            afr = zero8h();
        }
        v8h bh[4], bl[4];
        #pragma unroll
        for (int nt = 0; nt < 4; nt++) {
            bh[nt] = *reinterpret_cast<const v8h*>(&sBh[(nt * 16 + l16) * SBK + kb]);
            bl[nt] = *reinterpret_cast<const v8h*>(&sBl[(nt * 16 + l16) * SBK + kb]);
        }
        #pragma unroll
        for (int nt = 0; nt < 4; nt++) {
            acc[nt] = __builtin_amdgcn_mfma_f32_16x16x32_f16(afr, bh[nt], acc[nt], 0, 0, 0);
            acc[nt] = __builtin_amdgcn_mfma_f32_16x16x32_f16(afr, bl[nt], acc[nt], 0, 0, 0);
        }
    }

    // epilogue: D row = quad*4+reg, col = l16
    #pragma unroll
    for (int reg = 0; reg < 4; reg++) {
        const int node = nb + w * 16 + quad * 4 + reg;
        if (node < N_NODES) {
            const float dv = dinv[node];
            #pragma unroll
            for (int nt = 0; nt < 4; nt++)
                H16[(size_t)node * 64 + nt * 16 + l16] =
                    __float2half(acc[nt][reg] * dv);
        }
    }
}

// ---------------- FUSED prop(i)+gemm(i+1), zero-LDS-A version ----------------
// Lane (w, quad, l16) gathers channels {quad*8..+8, 32+quad*8..+8} of node
// v = nb + w*16 + l16 — after dinv+bias, these 16 floats ARE the two MFMA
// A-fragments (k-blocks 0 and 1). No sA tile, no transpose; LDS = W hi/lo
// only (18.4 KB). Same line-touches/edge as standalone prop (16 B/lane, both
// 64-B lines of each row covered). One barrier total.

__global__ __launch_bounds__(256) void k_pg(const __half* __restrict__ Hin,
                                            const int* __restrict__ csr,
                                            const int* __restrict__ offs,
                                            const int* __restrict__ deg_c,
                                            const float* __restrict__ dinv,
                                            const float* __restrict__ biasp,  // prop bias (layer i)
                                            const float* __restrict__ W,      // gemm weights (layer i+1)
                                            __half* __restrict__ H16out) {
    constexpr int SBK = 72;
    __shared__ __align__(16) _Float16 sBh[64 * SBK];
    __shared__ __align__(16) _Float16 sBl[64 * SBK];
    const int t = threadIdx.x;
    const int w = t >> 6, lane = t & 63;
    const int quad = lane >> 4, l16 = lane & 15;
    const int nb = blockIdx.x * 64;

    // stage W (64x64) -> transposed hi/lo [c][k]  (consumed after the barrier)
    for (int i = t; i < 64 * 16; i += 256) {
        const int k = i >> 4, c4 = (i & 15) * 4;
        const float4 wv = *reinterpret_cast<const float4*>(W + (size_t)k * 64 + c4);
        const float wf[4] = {wv.x, wv.y, wv.z, wv.w};
        #pragma unroll
        for (int j = 0; j < 4; j++) {
            const _Float16 hi = (_Float16)wf[j];
            sBh[(c4 + j) * SBK + k] = hi;
            sBl[(c4 + j) * SBK + k] = (_Float16)(wf[j] - (float)hi);
        }
    }

    // ---- prop phase: one node per l16, 16 channels per quad ----
    const int v = nb + w * 16 + l16;
    int cp = 0;
    const int* ep = csr;
    float dv = 0.0f;
    if (v < N_NODES) {
        ep = csr + offs[v];
        cp = (deg_c[v] + 7) & ~7;
        dv = dinv[v];
    }
    const __half* hlo = Hin + quad * 8;        // ch quad*8..+8     (16 B, line 0)
    const __half* hhi = Hin + 32 + quad * 8;   // ch 32+quad*8..+8  (16 B, line 1)
    float acl[8] = {0.f, 0.f, 0.f, 0.f, 0.f, 0.f, 0.f, 0.f};
    float ach[8] = {0.f, 0.f, 0.f, 0.f, 0.f, 0.f, 0.f, 0.f};
    #define ACC8(A, r) { \
        const float2 u0 = h2f(r.x), u1 = h2f(r.y); \
        const float2 u2 = h2f(r.z), u3 = h2f(r.w); \
        A[0] += u0.x; A[1] += u0.y; A[2] += u1.x; A[3] += u1.y; \
        A[4] += u2.x; A[5] += u2.y; A[6] += u3.x; A[7] += u3.y; }
    for (int j = 0; j < cp; j += 4) {          // per-lane trip count (exec mask)
        const vi4 e = __builtin_nontemporal_load(reinterpret_cast<const vi4*>(ep + j));
        const vi4 l0 = *reinterpret_cast<const vi4*>(hlo + (size_t)e.x * 64);
        const vi4 h0 = *reinterpret_cast<const vi4*>(hhi + (size_t)e.x * 64);
        const vi4 l1 = *reinterpret_cast<const vi4*>(hlo + (size_t)e.y * 64);
        const vi4 h1 = *reinterpret_cast<const vi4*>(hhi + (size_t)e.y * 64);
        const vi4 l2 = *reinterpret_cast<const vi4*>(hlo + (size_t)e.z * 64);
        const vi4 h2 = *reinterpret_cast<const vi4*>(hhi + (size_t)e.z * 64);
        const vi4 l3 = *reinterpret_cast<const vi4*>(hlo + (size_t)e.w * 64);
        const vi4 h3 = *reinterpret_cast<const vi4*>(hhi + (size_t)e.w * 64);
        ACC8(acl, l0) ACC8(ach, h0) ACC8(acl, l1) ACC8(ach, h1)
        ACC8(acl, l2) ACC8(ach, h2) ACC8(acl, l3) ACC8(ach, h3)
    }
    #undef ACC8

    // bias + dinv -> pack the two A-fragments (rounding identical to the old
    // prop-store/gemm-load fp16 boundary)
    const float4 b00 = *reinterpret_cast<const float4*>(biasp + quad * 8);
    const float4 b01 = *reinterpret_cast<const float4*>(biasp + quad * 8 + 4);
    const float4 b10 = *reinterpret_cast<const float4*>(biasp + 32 + quad * 8);
    const float4 b11 = *reinterpret_cast<const float4*>(biasp + 36 + quad * 8);
    v8h afr0, afr1;
    afr0[0] = (_Float16)(dv * acl[0] + b00.x); afr0[1] = (_Float16)(dv * acl[1] + b00.y);
    afr0[2] = (_Float16)(dv * acl[2] + b00.z); afr0[3] = (_Float16)(dv * acl[3] + b00.w);
    afr0[4] = (_Float16)(dv * acl[4] + b01.x); afr0[5] = (_Float16)(dv * acl[5] + b01.y);
    afr0[6] = (_Float16)(dv * acl[6] + b01.z); afr0[7] = (_Float16)(dv * acl[7] + b01.w);
    afr1[0] = (_Float16)(dv * ach[0] + b10.x); afr1[1] = (_Float16)(dv * ach[1] + b10.y);
    afr1[2] = (_Float16)(dv * ach[2] + b10.z); afr1[3] = (_Float16)(dv * ach[3] + b10.w);
    afr1[4] = (_Float16)(dv * ach[4] + b11.x); afr1[5] = (_Float16)(dv * ach[5] + b11.y);
    afr1[6] = (_Float16)(dv * ach[6] + b11.z); afr1[7] = (_Float16)(dv * ach[7] + b11.w);

    __syncthreads();   // W staged + all waves' fragments ready

    // ---- gemm phase: 16 MFMAs ----
    v4f acc[4] = {};
    #pragma unroll
    for (int nt = 0; nt < 4; nt++) {
        const int c = (nt * 16 + l16) * SBK;
        const v8h bh0 = *reinterpret_cast<const v8h*>(&sBh[c + quad * 8]);
        const v8h bl0 = *reinterpret_cast<const v8h*>(&sBl[c + quad * 8]);
        const v8h bh1 = *reinterpret_cast<const v8h*>(&sBh[c + 32 + quad * 8]);
        const v8h bl1 = *reinterpret_cast<const v8h*>(&sBl[c + 32 + quad * 8]);
        acc[nt] = __builtin_amdgcn_mfma_f32_16x16x32_f16(afr0, bh0, acc[nt], 0, 0, 0);
        acc[nt] = __builtin_amdgcn_mfma_f32_16x16x32_f16(afr0, bl0, acc[nt], 0, 0, 0);
        acc[nt] = __builtin_amdgcn_mfma_f32_16x16x32_f16(afr1, bh1, acc[nt], 0, 0, 0);
        acc[nt] = __builtin_amdgcn_mfma_f32_16x16x32_f16(afr1, bl1, acc[nt], 0, 0, 0);
    }

    // epilogue: D row = quad*4+reg, col = l16
    #pragma unroll
    for (int reg = 0; reg < 4; reg++) {
        const int node = nb + w * 16 + quad * 4 + reg;
        if (node < N_NODES) {
            const float dvo = dinv[node];
            #pragma unroll
            for (int nt = 0; nt < 4; nt++)
                H16out[(size_t)node * 64 + nt * 16 + l16] =
                    __float2half(acc[nt][reg] * dvo);
        }
    }
}

// ---------------- standalone propagation (layer 4): fp32 out for pooling ----------
// R7 structure: 4 nodes/wave; parity x 8 channel-groups; 16 B/lane gathers.

__global__ __launch_bounds__(256) void k_prop_f(const __half* __restrict__ Hin,
                                                const int* __restrict__ csr,
                                                const int* __restrict__ offs,
                                                const int* __restrict__ deg_c,
                                                const float* __restrict__ dinv,
                                                const float* __restrict__ bias,
                                                float* __restrict__ Hout) {
    const int wave = threadIdx.x >> 6, lane = threadIdx.x & 63;
    const int quad = lane >> 4;            // node slot within the wave
    const int par = (lane >> 3) & 1;       // edge parity
    const int cl = lane & 7;               // channels 8cl..8cl+7 (16 B)
    const int v = blockIdx.x * 16 + wave * 4 + quad;   // grid exact: v < N_NODES
    const int start = offs[v];
    const int cp = (deg_c[v] + 7) & ~7;
    const int* ep = csr + start;
    const __half* hb = Hin + cl * 8;
    float a0 = 0.f, a1 = 0.f, a2 = 0.f, a3 = 0.f;
    float a4 = 0.f, a5 = 0.f, a6 = 0.f, a7 = 0.f;
    for (int j = 0; j < cp; j += 8) {
        const vi4 q0 = __builtin_nontemporal_load(reinterpret_cast<const vi4*>(ep + j));
        const vi4 q1 = __builtin_nontemporal_load(reinterpret_cast<const vi4*>(ep + j + 4));
        const int ea = par ? q0.y : q0.x;
        const int eb = par ? q0.w : q0.z;
        const int ec = par ? q1.y : q1.x;
        const int ed = par ? q1.w : q1.z;
        const vi4 r0 = *reinterpret_cast<const vi4*>(hb + (size_t)ea * 64);
        const vi4 r1 = *reinterpret_cast<const vi4*>(hb + (size_t)eb * 64);
        const vi4 r2 = *reinterpret_cast<const vi4*>(hb + (size_t)ec * 64);
        const vi4 r3 = *reinterpret_cast<const vi4*>(hb + (size_t)ed * 64);
        #define ACC(r) { \
            const float2 u0 = h2f(r.x), u1 = h2f(r.y); \
            const float2 u2 = h2f(r.z), u3 = h2f(r.w); \
            a0 += u0.x; a1 += u0.y; a2 += u1.x; a3 += u1.y; \
            a4 += u2.x; a5 += u2.y; a6 += u3.x; a7 += u3.y; }
        ACC(r0) ACC(r1) ACC(r2) ACC(r3)
        #undef ACC
    }
    a0 += __shfl_xor(a0, 8); a1 += __shfl_xor(a1, 8);
    a2 += __shfl_xor(a2, 8); a3 += __shfl_xor(a3, 8);
    a4 += __shfl_xor(a4, 8); a5 += __shfl_xor(a5, 8);
    a6 += __shfl_xor(a6, 8); a7 += __shfl_xor(a7, 8);
    if (par == 0) {
        const float dv = dinv[v];
        const float4 b0 = *reinterpret_cast<const float4*>(bias + cl * 8);
        const float4 b1 = *reinterpret_cast<const float4*>(bias + cl * 8 + 4);
        vf4 olo; olo.x = dv * a0 + b0.x; olo.y = dv * a1 + b0.y;
        olo.z = dv * a2 + b0.z; olo.w = dv * a3 + b0.w;
        vf4 ohi; ohi.x = dv * a4 + b1.x; ohi.y = dv * a5 + b1.y;
        ohi.z = dv * a6 + b1.z; ohi.w = dv * a7 + b1.w;
        float* dst = Hout + (size_t)v * 64 + cl * 8;
        __builtin_nontemporal_store(olo, reinterpret_cast<vf4*>(dst));
        __builtin_nontemporal_store(ohi, reinterpret_cast<vf4*>(dst + 4));
    }
}

// ---------------- pooling + fused readout (last-block pattern) ----------------

__global__ __launch_bounds__(256) void k_pool(const float* __restrict__ H,
                                              const int* __restrict__ batch,
                                              float* partial,
                                              const float* __restrict__ Wl,
                                              const float* __restrict__ bl,
                                              float* __restrict__ out,
                                              int* done) {
    const int g = blockIdx.x >> 2;           // graph
    const int s = blockIdx.x & (SPLIT - 1);  // split
    int lo = 0, hi = N_NODES;
    while (lo < hi) { int m = (lo + hi) >> 1; if (batch[m] < g) lo = m + 1; else hi = m; }
    const int a = lo;
    lo = 0; hi = N_NODES;
    while (lo < hi) { int m = (lo + hi) >> 1; if (batch[m] < g + 1) lo = m + 1; else hi = m; }
    const int b = lo;

    const int wave = threadIdx.x >> 6, lane = threadIdx.x & 63;
    const int t = threadIdx.x;
    const int lane16 = s * 4 + wave;         // 0..15: stride position
    float ac0 = 0.f, ac1 = 0.f, ac2 = 0.f, ac3 = 0.f;
    int v = a + lane16;
    for (; v + 48 < b; v += 64) {
        ac0 += H[(size_t)v * 64 + lane];
        ac1 += H[(size_t)(v + 16) * 64 + lane];
        ac2 += H[(size_t)(v + 32) * 64 + lane];
        ac3 += H[(size_t)(v + 48) * 64 + lane];
    }
    for (; v < b; v += 16) ac0 += H[(size_t)v * 64 + lane];
    const float acc = (ac0 + ac1) + (ac2 + ac3);

    __shared__ float red[4][64];
    red[wave][lane] = acc;
    __syncthreads();
    if (wave == 0) {
        const float r = (red[0][lane] + red[1][lane]) + (red[2][lane] + red[3][lane]);
        partial[((size_t)s * N_GRAPHS + g) * 64 + lane] = r;
    }
    // ---- last block finishes the readout ----
    __threadfence();
    __syncthreads();
    __shared__ int lastflag;
    if (t == 0) lastflag = (atomicAdd(done, 1) == SPLIT * N_GRAPHS - 1);
    __syncthreads();
    if (!lastflag) return;
    __threadfence();

    __shared__ int cnts[128];
    if (t < 128) {
        int l0 = 0, h0 = N_NODES;
        while (l0 < h0) { int m = (l0 + h0) >> 1; if (batch[m] < t) l0 = m + 1; else h0 = m; }
        const int aa = l0;
        l0 = 0; h0 = N_NODES;
        while (l0 < h0) { int m = (l0 + h0) >> 1; if (batch[m] < t + 1) l0 = m + 1; else h0 = m; }
        cnts[t] = l0 - aa;
    }
    __syncthreads();
    for (int off = 64; off > 0; off >>= 1) {
        if (t < off && t + off < 128) cnts[t] = max(cnts[t], cnts[t + off]);
        __syncthreads();
    }
    const float nmax = (float)cnts[0];
    if (t < 128) {
        float sum = 0.f;
        for (int c = 0; c < 64; c++) {
            float gsum = 0.f;
            #pragma unroll
            for (int p = 0; p < SPLIT; p++)
                gsum += partial[((size_t)p * N_GRAPHS + t) * 64 + c];
            sum += gsum * Wl[c];
        }
        out[t] = sum / nmax + bl[0];
    }
}

// ---------------- launch ----------------

extern "C" void kernel_launch(void* const* d_in, const int* in_sizes, int n_in,
                              void* d_out, int out_size, void* d_ws, size_t ws_size,
                              hipStream_t stream) {
    const float* x    = (const float*)d_in[0];
    const int*   ei   = (const int*)d_in[1];     // [2, E] int32
    const int*   batch= (const int*)d_in[2];
    const float* W1 = (const float*)d_in[3];  const float* b1 = (const float*)d_in[4];
    const float* W2 = (const float*)d_in[5];  const float* b2 = (const float*)d_in[6];
    const float* W3 = (const float*)d_in[7];  const float* b3 = (const float*)d_in[8];
    const float* W4 = (const float*)d_in[9];  const float* b4 = (const float*)d_in[10];
    const float* Wl = (const float*)d_in[11]; const float* bl = (const float*)d_in[12];
    float* out = (float*)d_out;

    const int* row = ei;
    const int* col = ei + N_EDGES;

    // workspace layout (256B aligned blocks)
    char* ws = (char*)d_ws;
    size_t off = 0;
    auto alloc = [&](size_t bytes) {
        void* p = ws + off;
        off = (off + bytes + 255) & ~(size_t)255;
        return p;
    };
    int*    hist_t  = (int*)alloc((size_t)NB * BLK * 4);
    int*    cursors = (int*)alloc((size_t)NB * BLK * 4);
    int*    bcnt    = (int*)alloc(NB * 4);
    int*    bedges  = (int*)alloc((size_t)NB * CAP * 4);   // aliased by csr
    int*    csr     = bedges;                              // in-place rebuild (safe)
    int*    offs    = (int*)alloc(N_NODES * 4);
    int*    deg_c   = (int*)alloc(N_NODES * 4);
    float*  dinv    = (float*)alloc(N_NODES * 4);
    __half* h16a    = (__half*)alloc((size_t)(N_NODES + 1) * 64 * 2);  // gather table A
    __half* h16b    = (__half*)alloc((size_t)(N_NODES + 1) * 64 * 2);  // gather table B
    float*  h_b     = (float*)alloc((size_t)N_NODES * 64 * 4);         // fp32 prop output (layer 4)
    float*  partial = (float*)alloc((size_t)SPLIT * N_GRAPHS * 64 * 4);
    int*    done    = (int*)alloc(256);

    // CSR build (hist also zeroes sentinels + done counter)
    k_hist<<<BLK, 256, 0, stream>>>(col, hist_t, h16a, h16b, done);
    k_cursors<<<NB, 512, 0, stream>>>(hist_t, cursors, bcnt);
    k_mid<<<BLK, 256, 0, stream>>>(row, col, cursors, bedges);
    k_build<<<NB, 512, 0, stream>>>(bedges, bcnt, csr, offs, deg_c, dinv);

    const int GB = (N_NODES + 63) / 64;     // 1563 blocks (gemm1 / fused)
    const int PB = N_NODES / 16;            // 6250 prop blocks

    // layer 1 gemm, then fused prop+gemm chain, then layer-4 prop
    k_gemm<128><<<GB, 256, 0, stream>>>(x, W1, dinv, h16a);
    k_pg<<<GB, 256, 0, stream>>>(h16a, csr, offs, deg_c, dinv, b1, W2, h16b);
    k_pg<<<GB, 256, 0, stream>>>(h16b, csr, offs, deg_c, dinv, b2, W3, h16a);
    k_pg<<<GB, 256, 0, stream>>>(h16a, csr, offs, deg_c, dinv, b3, W4, h16b);
    k_prop_f<<<PB, 256, 0, stream>>>(h16b, csr, offs, deg_c, dinv, b4, h_b);

    // pooling + fused readout
    k_pool<<<N_GRAPHS * SPLIT, 256, 0, stream>>>(h_b, batch, partial, Wl, bl, out, done);
}